// Round 1
// baseline (340.372 us; speedup 1.0000x reference)
//
#include <hip/hip_runtime.h>
#include <stdint.h>

#define EPS_BN 1e-5f

// Problem geometry (fixed by setup_inputs)
#define BATCH 64
#define C 256
#define H 28
#define W 28
#define OHW 14
#define R196 196            // 14*14
#define M_TOT 12544         // 64*196
#define K1 2304             // 256*9

typedef __attribute__((ext_vector_type(8))) short bf16x8;
typedef __attribute__((ext_vector_type(4))) float f32x4;

__device__ __forceinline__ unsigned short sgn_bf16(float v) {
    // bf16 bit patterns: +1 = 0x3F80, -1 = 0xBF80, 0 = 0
    return v > 0.f ? (unsigned short)0x3F80
                   : (v < 0.f ? (unsigned short)0xBF80 : (unsigned short)0);
}

// ---------------------------------------------------------------------------
// Kernel 1: weight prep. 768 blocks x 256 thr.
//   blocks [0,256):   w1  -> bw1[oc][tap][ic] signs, alpha1/beta1 (BN folded)
//   blocks [256,512): w21 -> bw2[oc][ic],      alpha2/beta2 [0:256)
//   blocks [512,768): w22 -> bw2[256+oc][ic],  alpha2/beta2 [256:512)
// ---------------------------------------------------------------------------
__global__ void prep_weights(
    const float* __restrict__ w1,
    const float* __restrict__ bn1_g, const float* __restrict__ bn1_b,
    const float* __restrict__ bn1_m, const float* __restrict__ bn1_v,
    const float* __restrict__ w21,
    const float* __restrict__ bn21_g, const float* __restrict__ bn21_b,
    const float* __restrict__ bn21_m, const float* __restrict__ bn21_v,
    const float* __restrict__ w22,
    const float* __restrict__ bn22_g, const float* __restrict__ bn22_b,
    const float* __restrict__ bn22_m, const float* __restrict__ bn22_v,
    unsigned short* __restrict__ bw1, unsigned short* __restrict__ bw2,
    float* __restrict__ alpha1, float* __restrict__ beta1,
    float* __restrict__ alpha2, float* __restrict__ beta2)
{
    __shared__ float red[256];
    const int bid = blockIdx.x;
    const int t = threadIdx.x;

    if (bid < 256) {
        const int oc = bid;
        const float* w = w1 + oc * K1;
        float s = 0.f;
        for (int i = t; i < K1; i += 256) s += fabsf(w[i]);
        red[t] = s; __syncthreads();
        for (int o = 128; o > 0; o >>= 1) {
            if (t < o) red[t] += red[t + o];
            __syncthreads();
        }
        const float scale = red[0] * (1.f / (float)K1);
        if (t == 0) {
            const float inv = bn1_g[oc] * rsqrtf(bn1_v[oc] + EPS_BN);
            alpha1[oc] = scale * inv;
            beta1[oc]  = bn1_b[oc] - bn1_m[oc] * inv;
        }
        for (int i = t; i < K1; i += 256) {
            const int ic = i / 9, tap = i % 9;     // w1 flat: ic*9 + kh*3 + kw
            bw1[(oc * 9 + tap) * 256 + ic] = sgn_bf16(w[i]);
        }
    } else {
        const bool br2 = (bid >= 512);
        const int oc = (bid - 256) & 255;
        const float* w = (br2 ? w22 : w21) + oc * 256;
        red[t] = fabsf(w[t]); __syncthreads();
        for (int o = 128; o > 0; o >>= 1) {
            if (t < o) red[t] += red[t + o];
            __syncthreads();
        }
        const float scale = red[0] * (1.f / 256.f);
        const int n = oc + (br2 ? 256 : 0);
        if (t == 0) {
            const float g = br2 ? bn22_g[oc] : bn21_g[oc];
            const float b = br2 ? bn22_b[oc] : bn21_b[oc];
            const float m = br2 ? bn22_m[oc] : bn21_m[oc];
            const float v = br2 ? bn22_v[oc] : bn21_v[oc];
            const float inv = g * rsqrtf(v + EPS_BN);
            alpha2[n] = scale * inv;
            beta2[n]  = b - m * inv;
        }
        bw2[n * 256 + t] = sgn_bf16(w[t]);
    }
}

// ---------------------------------------------------------------------------
// Kernel 2: a1[b][ih][iw][ic] = sign(x[b][ic][ih][iw] + bias[ic])  (bf16 NHWC)
// ---------------------------------------------------------------------------
__global__ void sign_x_kernel(const float* __restrict__ x,
                              const float* __restrict__ bias,
                              unsigned short* __restrict__ a1, int total)
{
    for (int i = blockIdx.x * blockDim.x + threadIdx.x; i < total;
         i += gridDim.x * blockDim.x) {
        const int c = i & 255;
        int s = i >> 8;                 // (b*28+ih)*28+iw
        const int iw = s % 28; s /= 28;
        const int ih = s % 28; const int b = s / 28;
        const float v = x[((b * C + c) * H + ih) * W + iw] + bias[c];
        a1[i] = sgn_bf16(v);
    }
}

// ---------------------------------------------------------------------------
// Kernel 3: p[b][c][oh][ow] = 2x2 mean of x  (NCHW fp32)
// ---------------------------------------------------------------------------
__global__ void avgpool_kernel(const float* __restrict__ x,
                               float* __restrict__ p, int total)
{
    for (int i = blockIdx.x * blockDim.x + threadIdx.x; i < total;
         i += gridDim.x * blockDim.x) {
        const int ow = i % 14;
        int s = i / 14;
        const int oh = s % 14; s /= 14;     // s = b*C + c
        const int base = (s * H + 2 * oh) * W + 2 * ow;
        p[i] = 0.25f * (x[base] + x[base + 1] + x[base + W] + x[base + W + 1]);
    }
}

// ---------------------------------------------------------------------------
// Kernel 4: conv1 3x3 stride2 pad1 as 9 accumulated K=256 MFMA taps.
// Block = 4 waves; block -> mtile (16 m), wave -> ntile (64 n).
// D[row=n][col=m]; epilogue: alpha*S+beta + pool, RPReLU -> out2 (NCHW fp32).
// ---------------------------------------------------------------------------
__global__ __launch_bounds__(256) void conv1_kernel(
    const unsigned short* __restrict__ a1,   // [b][ih][iw][ic] bf16
    const unsigned short* __restrict__ bw1,  // [oc][tap][ic]   bf16
    const float* __restrict__ alpha1, const float* __restrict__ beta1,
    const float* __restrict__ p,             // [b][c][oh][ow]
    const float* __restrict__ prg, const float* __restrict__ prb,
    const float* __restrict__ prz,
    float* __restrict__ out2)                // [b][c][oh*14+ow]
{
    const int mtile = blockIdx.x;           // 0..783
    const int wave = threadIdx.x >> 6;      // 0..3 = ntile
    const int lane = threadIdx.x & 63;
    const int col = lane & 15;              // m sub-index (B free dim)
    const int krow = lane >> 4;             // k chunk / n sub-row
    const int m = mtile * 16 + col;
    const int b = m / R196;
    const int r = m % R196;
    const int oh = r / 14, ow = r % 14;
    const int nbase = wave * 64;

    const bf16x8 zfrag = {0, 0, 0, 0, 0, 0, 0, 0};
    f32x4 acc[4] = {};

    for (int tap = 0; tap < 9; ++tap) {
        const int kh = tap / 3, kw = tap % 3;
        const int ih = 2 * oh - 1 + kh;
        const int iw = 2 * ow - 1 + kw;
        const bool valid = ((unsigned)ih < (unsigned)H) && ((unsigned)iw < (unsigned)W);
        const unsigned short* act = a1 + (((b * H + ih) * W) + iw) * C + krow * 8;
        const unsigned short* wgt = bw1 + tap * 256 + krow * 8;
#pragma unroll
        for (int kc = 0; kc < 8; ++kc) {
            const bf16x8 bfrag = valid ? *(const bf16x8*)(act + kc * 32) : zfrag;
#pragma unroll
            for (int i = 0; i < 4; ++i) {
                const int n = nbase + i * 16 + col;
                const bf16x8 afrag = *(const bf16x8*)(wgt + n * K1 + kc * 32);
                acc[i] = __builtin_amdgcn_mfma_f32_16x16x32_bf16(afrag, bfrag, acc[i], 0, 0, 0);
            }
        }
    }

#pragma unroll
    for (int i = 0; i < 4; ++i) {
#pragma unroll
        for (int j = 0; j < 4; ++j) {
            const int n = nbase + i * 16 + krow * 4 + j;
            const int idx = (b * C + n) * R196 + r;
            float v = alpha1[n] * acc[i][j] + beta1[n] + p[idx];
            const float t = v - prg[n];
            out2[idx] = (t > 0.f ? t : prb[n] * t) + prz[n];
        }
    }
}

// ---------------------------------------------------------------------------
// Kernel 5: a2[m][ic] = sign(out2[b][ic][r] + bias[ic])  (bf16, m = b*196+r)
// ---------------------------------------------------------------------------
__global__ void sign_t_kernel(const float* __restrict__ out2,
                              const float* __restrict__ bias,
                              unsigned short* __restrict__ a2, int total)
{
    for (int i = blockIdx.x * blockDim.x + threadIdx.x; i < total;
         i += gridDim.x * blockDim.x) {
        const int c = i & 255;
        const int m = i >> 8;
        const int b = m / R196, r = m % R196;
        const float v = out2[(b * C + c) * R196 + r] + bias[c];
        a2[i] = sgn_bf16(v);
    }
}

// ---------------------------------------------------------------------------
// Kernel 6: both 1x1 convs as one M=12544, N=512, K=256 GEMM + fused epilogue.
// Block = 8 waves; block -> mtile, wave -> ntile. Writes d_out (concat NCHW).
// ---------------------------------------------------------------------------
__global__ __launch_bounds__(512) void conv1x1_kernel(
    const unsigned short* __restrict__ a2,   // [m][ic] bf16
    const unsigned short* __restrict__ bw2,  // [n'][ic] bf16, n' in [0,512)
    const float* __restrict__ alpha2, const float* __restrict__ beta2,
    const float* __restrict__ out2,          // [b][c][r] fp32
    const float* __restrict__ prg, const float* __restrict__ prb,
    const float* __restrict__ prz,
    float* __restrict__ out)                 // [b][n'][r], n' in [0,512)
{
    const int mtile = blockIdx.x;
    const int wave = threadIdx.x >> 6;       // 0..7 = ntile
    const int lane = threadIdx.x & 63;
    const int col = lane & 15;
    const int krow = lane >> 4;
    const int m = mtile * 16 + col;
    const int b = m / R196;
    const int r = m % R196;
    const int nbase = wave * 64;

    const unsigned short* act = a2 + m * 256 + krow * 8;
    f32x4 acc[4] = {};

#pragma unroll
    for (int kc = 0; kc < 8; ++kc) {
        const bf16x8 bfrag = *(const bf16x8*)(act + kc * 32);
#pragma unroll
        for (int i = 0; i < 4; ++i) {
            const int n = nbase + i * 16 + col;
            const bf16x8 afrag = *(const bf16x8*)(bw2 + n * 256 + kc * 32 + krow * 8);
            acc[i] = __builtin_amdgcn_mfma_f32_16x16x32_bf16(afrag, bfrag, acc[i], 0, 0, 0);
        }
    }

#pragma unroll
    for (int i = 0; i < 4; ++i) {
#pragma unroll
        for (int j = 0; j < 4; ++j) {
            const int n = nbase + i * 16 + krow * 4 + j;   // [0,512)
            const int oc = n & 255;
            float v = alpha2[n] * acc[i][j] + beta2[n] + out2[(b * C + oc) * R196 + r];
            const float t = v - prg[oc];
            out[(b * 512 + n) * R196 + r] = (t > 0.f ? t : prb[oc] * t) + prz[oc];
        }
    }
}

// ---------------------------------------------------------------------------
extern "C" void kernel_launch(void* const* d_in, const int* in_sizes, int n_in,
                              void* d_out, int out_size, void* d_ws, size_t ws_size,
                              hipStream_t stream)
{
    (void)in_sizes; (void)n_in; (void)out_size; (void)ws_size;

    const float* x         = (const float*)d_in[0];
    const float* rsign_b   = (const float*)d_in[1];
    const float* w1        = (const float*)d_in[2];
    const float* bn1_g     = (const float*)d_in[3];
    const float* bn1_b     = (const float*)d_in[4];
    const float* bn1_m     = (const float*)d_in[5];
    const float* bn1_v     = (const float*)d_in[6];
    const float* w21       = (const float*)d_in[7];
    const float* bn21_g    = (const float*)d_in[8];
    const float* bn21_b    = (const float*)d_in[9];
    const float* bn21_m    = (const float*)d_in[10];
    const float* bn21_v    = (const float*)d_in[11];
    const float* w22       = (const float*)d_in[12];
    const float* bn22_g    = (const float*)d_in[13];
    const float* bn22_b    = (const float*)d_in[14];
    const float* bn22_m    = (const float*)d_in[15];
    const float* bn22_v    = (const float*)d_in[16];
    const float* pr_gamma  = (const float*)d_in[17];
    const float* pr_beta   = (const float*)d_in[18];
    const float* pr_zeta   = (const float*)d_in[19];

    // workspace carve-up (total ~59.3 MB)
    char* ws = (char*)d_ws;
    size_t off = 0;
    unsigned short* a1  = (unsigned short*)(ws + off); off += (size_t)12845056 * 2; // 25.7MB
    unsigned short* bw1 = (unsigned short*)(ws + off); off += (size_t)589824 * 2;   // 1.2MB
    unsigned short* bw2 = (unsigned short*)(ws + off); off += (size_t)131072 * 2;   // 0.26MB
    float* pool         = (float*)(ws + off);          off += (size_t)3211264 * 4;  // 12.8MB
    float* out2         = (float*)(ws + off);          off += (size_t)3211264 * 4;  // 12.8MB
    unsigned short* a2  = (unsigned short*)(ws + off); off += (size_t)3211264 * 2;  // 6.4MB
    float* alpha1       = (float*)(ws + off);          off += 1024;
    float* beta1        = (float*)(ws + off);          off += 1024;
    float* alpha2       = (float*)(ws + off);          off += 2048;
    float* beta2        = (float*)(ws + off);          off += 2048;

    prep_weights<<<768, 256, 0, stream>>>(
        w1, bn1_g, bn1_b, bn1_m, bn1_v,
        w21, bn21_g, bn21_b, bn21_m, bn21_v,
        w22, bn22_g, bn22_b, bn22_m, bn22_v,
        bw1, bw2, alpha1, beta1, alpha2, beta2);

    sign_x_kernel<<<2048, 256, 0, stream>>>(x, rsign_b, a1, 12845056);
    avgpool_kernel<<<2048, 256, 0, stream>>>(x, pool, 3211264);

    conv1_kernel<<<784, 256, 0, stream>>>(
        a1, bw1, alpha1, beta1, pool, pr_gamma, pr_beta, pr_zeta, out2);

    sign_t_kernel<<<2048, 256, 0, stream>>>(out2, rsign_b, a2, 3211264);

    conv1x1_kernel<<<784, 512, 0, stream>>>(
        a2, bw2, alpha2, beta2, out2, pr_gamma, pr_beta, pr_zeta,
        (float*)d_out);
}

// Round 2
// 126.552 us; speedup vs baseline: 2.6896x; 2.6896x over previous
//
#include <hip/hip_runtime.h>
#include <stdint.h>

#define EPS_BN 1e-5f

// Geometry (fixed by setup_inputs)
#define C 256
#define H 28
#define W 28
#define R196 196            // 14*14
#define M_TOT 12544         // 64*196
#define K1 2304             // 256*9

typedef __attribute__((ext_vector_type(8))) short bf16x8;
typedef __attribute__((ext_vector_type(4))) float f32x4;
typedef __attribute__((ext_vector_type(4))) unsigned short u16x4;
typedef unsigned short ushort_t;

__device__ __forceinline__ unsigned short sgn_bf16(float v) {
    return v > 0.f ? (unsigned short)0x3F80
                   : (v < 0.f ? (unsigned short)0xBF80 : (unsigned short)0);
}

// async global->LDS, 16B per lane. LDS dest is wave-uniform base (+ lane*16 by HW).
__device__ __forceinline__ void gload16(const void* g, void* l) {
    __builtin_amdgcn_global_load_lds(
        (const __attribute__((address_space(1))) void*)g,
        (__attribute__((address_space(3))) void*)l, 16, 0, 0);
}

// ---------------------------------------------------------------------------
// Kernel 1: weight prep (unchanged from round 1).
// bw1[oc][tap][ic] -> row oc is K=2304 contiguous. bw2[n'][ic].
// ---------------------------------------------------------------------------
__global__ void prep_weights(
    const float* __restrict__ w1,
    const float* __restrict__ bn1_g, const float* __restrict__ bn1_b,
    const float* __restrict__ bn1_m, const float* __restrict__ bn1_v,
    const float* __restrict__ w21,
    const float* __restrict__ bn21_g, const float* __restrict__ bn21_b,
    const float* __restrict__ bn21_m, const float* __restrict__ bn21_v,
    const float* __restrict__ w22,
    const float* __restrict__ bn22_g, const float* __restrict__ bn22_b,
    const float* __restrict__ bn22_m, const float* __restrict__ bn22_v,
    unsigned short* __restrict__ bw1, unsigned short* __restrict__ bw2,
    float* __restrict__ alpha1, float* __restrict__ beta1,
    float* __restrict__ alpha2, float* __restrict__ beta2)
{
    __shared__ float red[256];
    const int bid = blockIdx.x;
    const int t = threadIdx.x;

    if (bid < 256) {
        const int oc = bid;
        const float* w = w1 + oc * K1;
        float s = 0.f;
        for (int i = t; i < K1; i += 256) s += fabsf(w[i]);
        red[t] = s; __syncthreads();
        for (int o = 128; o > 0; o >>= 1) {
            if (t < o) red[t] += red[t + o];
            __syncthreads();
        }
        const float scale = red[0] * (1.f / (float)K1);
        if (t == 0) {
            const float inv = bn1_g[oc] * rsqrtf(bn1_v[oc] + EPS_BN);
            alpha1[oc] = scale * inv;
            beta1[oc]  = bn1_b[oc] - bn1_m[oc] * inv;
        }
        for (int i = t; i < K1; i += 256) {
            const int ic = i / 9, tap = i % 9;     // w1 flat: ic*9 + kh*3 + kw
            bw1[(oc * 9 + tap) * 256 + ic] = sgn_bf16(w[i]);
        }
    } else {
        const bool br2 = (bid >= 512);
        const int oc = (bid - 256) & 255;
        const float* w = (br2 ? w22 : w21) + oc * 256;
        red[t] = fabsf(w[t]); __syncthreads();
        for (int o = 128; o > 0; o >>= 1) {
            if (t < o) red[t] += red[t + o];
            __syncthreads();
        }
        const float scale = red[0] * (1.f / 256.f);
        const int n = oc + (br2 ? 256 : 0);
        if (t == 0) {
            const float g = br2 ? bn22_g[oc] : bn21_g[oc];
            const float b = br2 ? bn22_b[oc] : bn21_b[oc];
            const float m = br2 ? bn22_m[oc] : bn21_m[oc];
            const float v = br2 ? bn22_v[oc] : bn21_v[oc];
            const float inv = g * rsqrtf(v + EPS_BN);
            alpha2[n] = scale * inv;
            beta2[n]  = b - m * inv;
        }
        bw2[n * 256 + t] = sgn_bf16(w[t]);
    }
}

// ---------------------------------------------------------------------------
// Kernel 2: a1p[b][ihp][iwp][c] = sign(x[b][c][ih][iw]+bias[c]), padded 30x30,
// zero halo. One block per (b, ih): coalesced x read via LDS transpose,
// coalesced NHWC write.
// ---------------------------------------------------------------------------
__global__ __launch_bounds__(256) void sign_x_pad(
    const float* __restrict__ x, const float* __restrict__ bias,
    ushort_t* __restrict__ a1p)
{
    __shared__ float lx[256][29];
    const int bh = blockIdx.x;               // b*28 + ih
    const int b = bh / 28, ih = bh % 28;
    const int t = threadIdx.x;
    const float* xb = x + (size_t)(b * 256) * 784 + ih * 28;

    for (int idx = t; idx < 28 * 256; idx += 256) {
        const int c = idx / 28, iw = idx % 28;       // iw fastest -> coalesced
        lx[c][iw] = xb[c * 784 + iw];
    }
    __syncthreads();
    ushort_t* orow = a1p + (size_t)((b * 30 + ih + 1) * 30) * 256;
    for (int idx = t; idx < 28 * 256; idx += 256) {
        const int c = idx & 255, iw = idx >> 8;      // c fastest -> coalesced
        orow[(iw + 1) * 256 + c] = sgn_bf16(lx[c][iw] + bias[c]);
    }
    // halo columns iwp = 0, 29 of this row
    orow[t] = 0;
    orow[29 * 256 + t] = 0;
    // halo rows ihp = 0, 29 (done by ih==0 blocks)
    if (ih == 0) {
        ushort_t* r0  = a1p + (size_t)(b * 900) * 256;
        ushort_t* r29 = a1p + (size_t)(b * 900 + 29 * 30) * 256;
        for (int idx = t; idx < 30 * 256; idx += 256) { r0[idx] = 0; r29[idx] = 0; }
    }
}

// ---------------------------------------------------------------------------
// Kernel 3: avgpool (unchanged)
// ---------------------------------------------------------------------------
__global__ void avgpool_kernel(const float* __restrict__ x,
                               float* __restrict__ p, int total)
{
    for (int i = blockIdx.x * blockDim.x + threadIdx.x; i < total;
         i += gridDim.x * blockDim.x) {
        const int ow = i % 14;
        int s = i / 14;
        const int oh = s % 14; s /= 14;     // s = b*C + c
        const int base = (s * H + 2 * oh) * W + 2 * ow;
        p[i] = 0.25f * (x[base] + x[base + 1] + x[base + W] + x[base + W + 1]);
    }
}

// ---------------------------------------------------------------------------
// Kernel 4: conv1 (3x3 s2) as LDS-staged GEMM. M=12544, N=256, K=2304.
// BM=128, BN=64, BK=64. 392 blocks (98 mtiles x 4 ntiles), 4 waves (2m x 2n),
// wave tile 64x32. XOR-swizzled LDS (slot ^= row&7), global_load_lds width 16.
// Epilogue: BN-fold + avgpool residual + RPReLU -> out2; sign(+bias) -> a2.
// ---------------------------------------------------------------------------
__global__ __launch_bounds__(256) void conv1_lds(
    const ushort_t* __restrict__ a1p,   // [64][30][30][256] bf16, padded
    const ushort_t* __restrict__ bw1,   // [256][2304] bf16
    const float* __restrict__ alpha1, const float* __restrict__ beta1,
    const float* __restrict__ p,        // [b][c][196]
    const float* __restrict__ rsb,
    const float* __restrict__ prg, const float* __restrict__ prb,
    const float* __restrict__ prz,
    float* __restrict__ out2,           // [b][c][196]
    ushort_t* __restrict__ a2)          // [m][256]
{
    __shared__ ushort_t lA[128 * 64];   // acts  [m-row][64k], swizzled
    __shared__ ushort_t lB[64 * 64];    // wgts  [n-row][64k], swizzled

    const int bid = blockIdx.x;
    const int wgid = (bid & 7) * 49 + (bid >> 3);   // bijective XCD swizzle (392=8*49)
    const int mtile = wgid % 98;
    const int ntile = wgid / 98;        // 0..3

    const int tid = threadIdx.x;
    const int wave = tid >> 6;
    const int lane = tid & 63;
    const int col = lane & 15;
    const int krow = lane >> 4;
    const int wr = wave >> 1;           // m half
    const int wc = wave & 1;            // n half
    const int l8 = lane >> 3;           // staging row-within-8 (== row&7)
    const int s8 = lane & 7;            // staging slot
    const int swz = ((s8 ^ l8) << 3);   // pre-swizzled source column (elements)

    // staging source bases (element offsets), constant over K-loop
    int pb[4];
#pragma unroll
    for (int l = 0; l < 4; ++l) {
        const int row = (wave * 4 + l) * 8 + l8;
        const int m = mtile * 128 + row;
        const int b = m / 196, r = m % 196;
        const int oh = r / 14, ow = r % 14;
        pb[l] = ((b * 30 + 2 * oh) * 30 + 2 * ow) * 256 + swz;
    }
    int wb[2];
#pragma unroll
    for (int l = 0; l < 2; ++l) {
        const int row = (wave * 2 + l) * 8 + l8;
        wb[l] = (ntile * 64 + row) * K1 + swz;
    }

    // frag-read swizzled byte offsets within a 128B LDS row (row&7 == col&7)
    int rswz[2];
#pragma unroll
    for (int ks = 0; ks < 2; ++ks)
        rswz[ks] = ((ks * 4 + krow) ^ (col & 7)) << 4;

    f32x4 acc[4][2] = {};

    for (int step = 0; step < 36; ++step) {
        const int tap = step >> 2;
        const int kc0 = (step & 3) << 6;
        const int kh = tap / 3, kw = tap - kh * 3;
        const int aoff = (kh * 30 + kw) * 256 + kc0;
#pragma unroll
        for (int l = 0; l < 4; ++l)
            gload16(a1p + pb[l] + aoff, (char*)lA + (wave * 4 + l) * 1024);
#pragma unroll
        for (int l = 0; l < 2; ++l)
            gload16(bw1 + wb[l] + step * 64, (char*)lB + (wave * 2 + l) * 1024);
        __syncthreads();   // drains vmcnt + barrier

#pragma unroll
        for (int ks = 0; ks < 2; ++ks) {
            bf16x8 bf[4], af[2];
#pragma unroll
            for (int im = 0; im < 4; ++im) {
                const int row = wr * 64 + im * 16 + col;
                bf[im] = *(const bf16x8*)((const char*)lA + row * 128 + rswz[ks]);
            }
#pragma unroll
            for (int in = 0; in < 2; ++in) {
                const int row = wc * 32 + in * 16 + col;
                af[in] = *(const bf16x8*)((const char*)lB + row * 128 + rswz[ks]);
            }
#pragma unroll
            for (int im = 0; im < 4; ++im)
#pragma unroll
                for (int in = 0; in < 2; ++in)
                    acc[im][in] = __builtin_amdgcn_mfma_f32_16x16x32_bf16(
                        af[in], bf[im], acc[im][in], 0, 0, 0);
        }
        __syncthreads();   // protect LDS before next stage
    }

    // epilogue
#pragma unroll
    for (int im = 0; im < 4; ++im) {
        const int m = mtile * 128 + wr * 64 + im * 16 + col;
        const int b = m / 196, r = m % 196;
#pragma unroll
        for (int in = 0; in < 2; ++in) {
            const int n0 = ntile * 64 + wc * 32 + in * 16 + krow * 4;
            u16x4 spack;
#pragma unroll
            for (int j = 0; j < 4; ++j) {
                const int n = n0 + j;
                const int idx = (b * 256 + n) * 196 + r;
                float v = alpha1[n] * acc[im][in][j] + beta1[n] + p[idx];
                const float t = v - prg[n];
                const float o = (t > 0.f ? t : prb[n] * t) + prz[n];
                out2[idx] = o;
                spack[j] = sgn_bf16(o + rsb[n]);
            }
            *(u16x4*)(a2 + m * 256 + n0) = spack;
        }
    }
}

// ---------------------------------------------------------------------------
// Kernel 5: both 1x1 convs as one LDS-staged GEMM. M=12544, N=512, K=256.
// Same structure as conv1_lds, 4 K-steps. 784 blocks (98 x 8 ntiles).
// Epilogue: BN-fold + out2 residual + RPReLU -> d_out (concat for free).
// ---------------------------------------------------------------------------
__global__ __launch_bounds__(256) void conv1x1_lds(
    const ushort_t* __restrict__ a2,    // [m][256] bf16
    const ushort_t* __restrict__ bw2,   // [512][256] bf16
    const float* __restrict__ alpha2, const float* __restrict__ beta2,
    const float* __restrict__ out2,     // [b][c][196]
    const float* __restrict__ prg, const float* __restrict__ prb,
    const float* __restrict__ prz,
    float* __restrict__ out)            // [b][512][196]
{
    __shared__ ushort_t lA[128 * 64];
    __shared__ ushort_t lB[64 * 64];

    const int bid = blockIdx.x;
    const int wgid = (bid & 7) * 98 + (bid >> 3);   // 784 = 8*98
    const int mtile = wgid % 98;
    const int ntile = wgid / 98;        // 0..7

    const int tid = threadIdx.x;
    const int wave = tid >> 6;
    const int lane = tid & 63;
    const int col = lane & 15;
    const int krow = lane >> 4;
    const int wr = wave >> 1;
    const int wc = wave & 1;
    const int l8 = lane >> 3;
    const int s8 = lane & 7;
    const int swz = ((s8 ^ l8) << 3);

    int pb[4];
#pragma unroll
    for (int l = 0; l < 4; ++l) {
        const int row = (wave * 4 + l) * 8 + l8;
        pb[l] = (mtile * 128 + row) * 256 + swz;
    }
    int wb[2];
#pragma unroll
    for (int l = 0; l < 2; ++l) {
        const int row = (wave * 2 + l) * 8 + l8;
        wb[l] = (ntile * 64 + row) * 256 + swz;
    }
    int rswz[2];
#pragma unroll
    for (int ks = 0; ks < 2; ++ks)
        rswz[ks] = ((ks * 4 + krow) ^ (col & 7)) << 4;

    f32x4 acc[4][2] = {};

    for (int step = 0; step < 4; ++step) {
#pragma unroll
        for (int l = 0; l < 4; ++l)
            gload16(a2 + pb[l] + step * 64, (char*)lA + (wave * 4 + l) * 1024);
#pragma unroll
        for (int l = 0; l < 2; ++l)
            gload16(bw2 + wb[l] + step * 64, (char*)lB + (wave * 2 + l) * 1024);
        __syncthreads();

#pragma unroll
        for (int ks = 0; ks < 2; ++ks) {
            bf16x8 bf[4], af[2];
#pragma unroll
            for (int im = 0; im < 4; ++im) {
                const int row = wr * 64 + im * 16 + col;
                bf[im] = *(const bf16x8*)((const char*)lA + row * 128 + rswz[ks]);
            }
#pragma unroll
            for (int in = 0; in < 2; ++in) {
                const int row = wc * 32 + in * 16 + col;
                af[in] = *(const bf16x8*)((const char*)lB + row * 128 + rswz[ks]);
            }
#pragma unroll
            for (int im = 0; im < 4; ++im)
#pragma unroll
                for (int in = 0; in < 2; ++in)
                    acc[im][in] = __builtin_amdgcn_mfma_f32_16x16x32_bf16(
                        af[in], bf[im], acc[im][in], 0, 0, 0);
        }
        __syncthreads();
    }

#pragma unroll
    for (int im = 0; im < 4; ++im) {
        const int m = mtile * 128 + wr * 64 + im * 16 + col;
        const int b = m / 196, r = m % 196;
#pragma unroll
        for (int in = 0; in < 2; ++in) {
#pragma unroll
            for (int j = 0; j < 4; ++j) {
                const int n = ntile * 64 + wc * 32 + in * 16 + krow * 4 + j;  // [0,512)
                const int oc = n & 255;
                float v = alpha2[n] * acc[im][in][j] + beta2[n]
                        + out2[(b * 256 + oc) * 196 + r];
                const float t = v - prg[oc];
                out[(size_t)(b * 512 + n) * 196 + r] =
                    (t > 0.f ? t : prb[oc] * t) + prz[oc];
            }
        }
    }
}

// ---------------------------------------------------------------------------
extern "C" void kernel_launch(void* const* d_in, const int* in_sizes, int n_in,
                              void* d_out, int out_size, void* d_ws, size_t ws_size,
                              hipStream_t stream)
{
    (void)in_sizes; (void)n_in; (void)out_size; (void)ws_size;

    const float* x         = (const float*)d_in[0];
    const float* rsign_b   = (const float*)d_in[1];
    const float* w1        = (const float*)d_in[2];
    const float* bn1_g     = (const float*)d_in[3];
    const float* bn1_b     = (const float*)d_in[4];
    const float* bn1_m     = (const float*)d_in[5];
    const float* bn1_v     = (const float*)d_in[6];
    const float* w21       = (const float*)d_in[7];
    const float* bn21_g    = (const float*)d_in[8];
    const float* bn21_b    = (const float*)d_in[9];
    const float* bn21_m    = (const float*)d_in[10];
    const float* bn21_v    = (const float*)d_in[11];
    const float* w22       = (const float*)d_in[12];
    const float* bn22_g    = (const float*)d_in[13];
    const float* bn22_b    = (const float*)d_in[14];
    const float* bn22_m    = (const float*)d_in[15];
    const float* bn22_v    = (const float*)d_in[16];
    const float* pr_gamma  = (const float*)d_in[17];
    const float* pr_beta   = (const float*)d_in[18];
    const float* pr_zeta   = (const float*)d_in[19];

    // workspace carve-up (~63.1 MB)
    char* ws = (char*)d_ws;
    size_t off = 0;
    ushort_t* a1p = (ushort_t*)(ws + off); off += (size_t)14745600 * 2; // 29.5MB padded acts
    ushort_t* bw1 = (ushort_t*)(ws + off); off += (size_t)589824 * 2;   // 1.2MB
    ushort_t* bw2 = (ushort_t*)(ws + off); off += (size_t)131072 * 2;   // 0.26MB
    float* pool   = (float*)(ws + off);    off += (size_t)3211264 * 4;  // 12.8MB
    float* out2   = (float*)(ws + off);    off += (size_t)3211264 * 4;  // 12.8MB
    ushort_t* a2  = (ushort_t*)(ws + off); off += (size_t)3211264 * 2;  // 6.4MB
    float* alpha1 = (float*)(ws + off);    off += 1024;
    float* beta1  = (float*)(ws + off);    off += 1024;
    float* alpha2 = (float*)(ws + off);    off += 2048;
    float* beta2  = (float*)(ws + off);    off += 2048;

    prep_weights<<<768, 256, 0, stream>>>(
        w1, bn1_g, bn1_b, bn1_m, bn1_v,
        w21, bn21_g, bn21_b, bn21_m, bn21_v,
        w22, bn22_g, bn22_b, bn22_m, bn22_v,
        bw1, bw2, alpha1, beta1, alpha2, beta2);

    sign_x_pad<<<64 * 28, 256, 0, stream>>>(x, rsign_b, a1p);
    avgpool_kernel<<<2048, 256, 0, stream>>>(x, pool, 3211264);

    conv1_lds<<<392, 256, 0, stream>>>(
        a1p, bw1, alpha1, beta1, pool, rsign_b,
        pr_gamma, pr_beta, pr_zeta, out2, a2);

    conv1x1_lds<<<784, 256, 0, stream>>>(
        a2, bw2, alpha2, beta2, out2,
        pr_gamma, pr_beta, pr_zeta, (float*)d_out);
}